// Round 1
// baseline (86.906 us; speedup 1.0000x reference)
//
#include <hip/hip_runtime.h>
#include <hip/hip_bf16.h>

// QLoRA SwiGLU MLP, B=16 tokens, d=4096, h=11008, r=2.
// Key algebraic fold: tile(wq,(1,4)) => x @ W^T == fold4(x) @ wq^T,
// so each linear is a skinny GEMM with K = in/4 against the compressed weight.
// LoRA (r=2) is a 16x2 intermediate, fused into epilogues.

#define NB     16
#define DMODEL 4096
#define HID    11008
#define DQ     1024   // DMODEL/4
#define HQ     2752   // HID/4

// workspace layout (float offsets)
#define XS1_OFF 0                         // [16][1024]
#define T1_OFF  16384                     // [16][2]
#define T3_OFF  16416                     // [16][2]
#define HVT_OFF 16448                     // hvecT [11008][16]
#define HS_OFF  192576                    // hs [16][2752]
#define T2_OFF  236608                    // [16][2]

// ---------------------------------------------------------------------------
// prep1: xs[b][j] = sum_k x[b][k*1024+j];  t1[b][r]=x[b]·a1[r]; t3 likewise.
// grid 16 (one block per token), 256 threads.
__global__ __launch_bounds__(256) void k_prep1(const float* __restrict__ x,
                                               const float* __restrict__ a1,
                                               const float* __restrict__ a3,
                                               float* __restrict__ ws) {
  const int b = blockIdx.x, t = threadIdx.x;
  const float4* x4  = (const float4*)(x) + b * (DMODEL / 4);
  const float4* a14 = (const float4*)a1;   // (2,4096) -> 2 rows of 1024 float4
  const float4* a34 = (const float4*)a3;
  float4 xs = make_float4(0.f, 0.f, 0.f, 0.f);
  float s10 = 0.f, s11 = 0.f, s30 = 0.f, s31 = 0.f;
#pragma unroll
  for (int k = 0; k < 4; ++k) {
    float4 xv  = x4[k * 256 + t];
    xs.x += xv.x; xs.y += xv.y; xs.z += xv.z; xs.w += xv.w;
    float4 a10 = a14[k * 256 + t];
    float4 a11 = a14[1024 + k * 256 + t];
    float4 a30 = a34[k * 256 + t];
    float4 a31 = a34[1024 + k * 256 + t];
    s10 += xv.x * a10.x + xv.y * a10.y + xv.z * a10.z + xv.w * a10.w;
    s11 += xv.x * a11.x + xv.y * a11.y + xv.z * a11.z + xv.w * a11.w;
    s30 += xv.x * a30.x + xv.y * a30.y + xv.z * a30.z + xv.w * a30.w;
    s31 += xv.x * a31.x + xv.y * a31.y + xv.z * a31.z + xv.w * a31.w;
  }
  ((float4*)(ws + XS1_OFF))[b * 256 + t] = xs;

  __shared__ float4 rb[256];
  rb[t] = make_float4(s10, s11, s30, s31);
  __syncthreads();
  for (int s = 128; s > 0; s >>= 1) {
    if (t < s) {
      rb[t].x += rb[t + s].x; rb[t].y += rb[t + s].y;
      rb[t].z += rb[t + s].z; rb[t].w += rb[t + s].w;
    }
    __syncthreads();
  }
  if (t == 0) {
    ws[T1_OFF + b * 2]     = rb[0].x;
    ws[T1_OFF + b * 2 + 1] = rb[0].y;
    ws[T3_OFF + b * 2]     = rb[0].z;
    ws[T3_OFF + b * 2 + 1] = rb[0].w;
  }
}

// ---------------------------------------------------------------------------
// gateup: hvecT[o][b] = silu(g) * u for all 16 tokens, wave-per-output-column.
// Both w1 and w3 rows swept per wave so the LDS xs read is shared.
// grid HID/8 = 1376, 512 threads (8 waves); 64 KB LDS -> 2 blocks/CU.
__global__ __launch_bounds__(512) void k_gateup(const float* __restrict__ w1q,
                                                const float* __restrict__ w3q,
                                                const float* __restrict__ b1,
                                                const float* __restrict__ b3,
                                                const float* __restrict__ ws,
                                                float* __restrict__ hvecT) {
  __shared__ float4 lds[16 * 256];   // xs, 16 tokens x 1024 floats = 64 KB
  const int t = threadIdx.x;
  const float4* xs4 = (const float4*)(ws + XS1_OFF);
  for (int i = t; i < 4096; i += 512) lds[i] = xs4[i];
  __syncthreads();

  const int wave = t >> 6, lane = t & 63;
  const int o = blockIdx.x * 8 + wave;
  const float4* w14 = (const float4*)(w1q) + o * 256;  // K=1024 -> 256 float4
  const float4* w34 = (const float4*)(w3q) + o * 256;

  float acc1[16], acc3[16];
#pragma unroll
  for (int b = 0; b < 16; ++b) { acc1[b] = 0.f; acc3[b] = 0.f; }

#pragma unroll
  for (int c = 0; c < 4; ++c) {
    const int idx = c * 64 + lane;
    float4 w1v = w14[idx];
    float4 w3v = w34[idx];
#pragma unroll
    for (int b = 0; b < 16; ++b) {
      float4 xv = lds[b * 256 + idx];
      acc1[b] += w1v.x * xv.x + w1v.y * xv.y + w1v.z * xv.z + w1v.w * xv.w;
      acc3[b] += w3v.x * xv.x + w3v.y * xv.y + w3v.z * xv.z + w3v.w * xv.w;
    }
  }

  float g = 0.f, u = 0.f;
#pragma unroll
  for (int b = 0; b < 16; ++b) {
    float r1 = acc1[b], r3 = acc3[b];
#pragma unroll
    for (int off = 32; off > 0; off >>= 1) {
      r1 += __shfl_xor(r1, off);
      r3 += __shfl_xor(r3, off);
    }
    if (lane == b) { g = r1; u = r3; }
  }
  if (lane < 16) {
    const int b = lane;
    const float gl = g + 0.5f * (ws[T1_OFF + b * 2] * b1[o * 2] +
                                 ws[T1_OFF + b * 2 + 1] * b1[o * 2 + 1]);
    const float ul = u + 0.5f * (ws[T3_OFF + b * 2] * b3[o * 2] +
                                 ws[T3_OFF + b * 2 + 1] * b3[o * 2 + 1]);
    const float sg = gl / (1.0f + __expf(-gl));   // silu
    hvecT[o * 16 + b] = sg * ul;
  }
}

// ---------------------------------------------------------------------------
// prep2: hs[b][j] = sum_k hvec[b][k*2752+j] (j<2752); t2[b][r] = hvec[b]·a2[r]
// grid 16, 256 threads.
__global__ __launch_bounds__(256) void k_prep2(const float* __restrict__ hvecT,
                                               const float* __restrict__ a2,
                                               float* __restrict__ ws) {
  const int b = blockIdx.x, t = threadIdx.x;
  float s0 = 0.f, s1 = 0.f;
  float* hs = ws + HS_OFF;
  for (int j = t; j < HQ; j += 256) {
    float v0 = hvecT[j * 16 + b];
    float v1 = hvecT[(j + HQ) * 16 + b];
    float v2 = hvecT[(j + 2 * HQ) * 16 + b];
    float v3 = hvecT[(j + 3 * HQ) * 16 + b];
    hs[b * HQ + j] = v0 + v1 + v2 + v3;
    s0 += v0 * a2[j] + v1 * a2[j + HQ] + v2 * a2[j + 2 * HQ] + v3 * a2[j + 3 * HQ];
    s1 += v0 * a2[HID + j] + v1 * a2[HID + j + HQ] +
          v2 * a2[HID + j + 2 * HQ] + v3 * a2[HID + j + 3 * HQ];
  }
  __shared__ float2 rb[256];
  rb[t] = make_float2(s0, s1);
  __syncthreads();
  for (int s = 128; s > 0; s >>= 1) {
    if (t < s) { rb[t].x += rb[t + s].x; rb[t].y += rb[t + s].y; }
    __syncthreads();
  }
  if (t == 0) { ws[T2_OFF + b * 2] = rb[0].x; ws[T2_OFF + b * 2 + 1] = rb[0].y; }
}

// ---------------------------------------------------------------------------
// down: out[b][o] = hs[b]·w2q[o] + 0.5*lora2;  K=2752 in 3 LDS chunks.
// grid DMODEL/8 = 512, 512 threads.
__global__ __launch_bounds__(512) void k_down(const float* __restrict__ w2q,
                                              const float* __restrict__ b2,
                                              const float* __restrict__ ws,
                                              float* __restrict__ out) {
  __shared__ float4 lds[16 * 256];
  const int t = threadIdx.x, wave = t >> 6, lane = t & 63;
  const int o = blockIdx.x * 8 + wave;
  const float4* w24 = (const float4*)(w2q) + o * 688;   // K=2752 -> 688 float4
  const float4* hs4 = (const float4*)(ws + HS_OFF);

  float acc[16];
#pragma unroll
  for (int b = 0; b < 16; ++b) acc[b] = 0.f;

  for (int c0 = 0; c0 < 688; c0 += 256) {
    const int nc = (688 - c0) < 256 ? (688 - c0) : 256;   // 256,256,176
    __syncthreads();
    for (int i = t; i < 4096; i += 512) {
      const int row = i >> 8, col = i & 255;
      if (col < nc) lds[row * 256 + col] = hs4[row * 688 + c0 + col];
    }
    __syncthreads();
    for (int idx = lane; idx < nc; idx += 64) {
      float4 wv = w24[c0 + idx];
#pragma unroll
      for (int b = 0; b < 16; ++b) {
        float4 xv = lds[b * 256 + idx];
        acc[b] += wv.x * xv.x + wv.y * xv.y + wv.z * xv.z + wv.w * xv.w;
      }
    }
  }

  float r = 0.f;
#pragma unroll
  for (int b = 0; b < 16; ++b) {
    float v = acc[b];
#pragma unroll
    for (int off = 32; off > 0; off >>= 1) v += __shfl_xor(v, off);
    if (lane == b) r = v;
  }
  if (lane < 16) {
    const int b = lane;
    out[b * DMODEL + o] = r + 0.5f * (ws[T2_OFF + b * 2] * b2[o * 2] +
                                      ws[T2_OFF + b * 2 + 1] * b2[o * 2 + 1]);
  }
}

// ---------------------------------------------------------------------------
extern "C" void kernel_launch(void* const* d_in, const int* in_sizes, int n_in,
                              void* d_out, int out_size, void* d_ws, size_t ws_size,
                              hipStream_t stream) {
  const float* x   = (const float*)d_in[0];
  const float* w1q = (const float*)d_in[1];
  const float* a1  = (const float*)d_in[2];
  const float* b1  = (const float*)d_in[3];
  const float* w3q = (const float*)d_in[4];
  const float* a3  = (const float*)d_in[5];
  const float* b3  = (const float*)d_in[6];
  const float* w2q = (const float*)d_in[7];
  const float* a2  = (const float*)d_in[8];
  const float* b2  = (const float*)d_in[9];
  float* out = (float*)d_out;
  float* ws  = (float*)d_ws;
  float* hvecT = ws + HVT_OFF;

  k_prep1<<<16, 256, 0, stream>>>(x, a1, a3, ws);
  k_gateup<<<HID / 8, 512, 0, stream>>>(w1q, w3q, b1, b3, ws, hvecT);
  k_prep2<<<16, 256, 0, stream>>>(hvecT, a2, ws);
  k_down<<<DMODEL / 8, 512, 0, stream>>>(w2q, b2, ws, out);
}